// Round 6
// baseline (217.224 us; speedup 1.0000x reference)
//
#include <hip/hip_runtime.h>

#define PP 8732
#define NB 20
#define NC 21
#define BTH 256
#define CHP 512         // match: priors per block (2 per lane, 128 per wave)
#define NCH 18          // ceil(PP/CHP)
#define NLS 35          // lse: ceil(PP/256)
#define BTS 1024
#define NWS (BTS/64)

__device__ __forceinline__ float sl1(float d){
  float a = fabsf(d);
  return a < 1.0f ? 0.5f*a*a : a - 0.5f;
}

// Full 64-lane max via DPP (VALU pipe only); result valid in lane 63, broadcast
// to all lanes through readlane. bound_ctrl=1 injects 0.0 at row edges -- harmless
// here since every participating value is >= 0 (candiou is an IoU >= 0).
__device__ __forceinline__ float wave_max64(float x){
  int t;
  t = __builtin_amdgcn_update_dpp(0, __float_as_int(x), 0x111, 0xF, 0xF, true); x = fmaxf(x, __int_as_float(t));
  t = __builtin_amdgcn_update_dpp(0, __float_as_int(x), 0x112, 0xF, 0xF, true); x = fmaxf(x, __int_as_float(t));
  t = __builtin_amdgcn_update_dpp(0, __float_as_int(x), 0x114, 0xF, 0xF, true); x = fmaxf(x, __int_as_float(t));
  t = __builtin_amdgcn_update_dpp(0, __float_as_int(x), 0x118, 0xF, 0xF, true); x = fmaxf(x, __int_as_float(t));
  t = __builtin_amdgcn_update_dpp(0, __float_as_int(x), 0x142, 0xF, 0xF, true); x = fmaxf(x, __int_as_float(t));
  t = __builtin_amdgcn_update_dpp(0, __float_as_int(x), 0x143, 0xF, 0xF, true); x = fmaxf(x, __int_as_float(t));
  return __int_as_float(__builtin_amdgcn_readlane(__float_as_int(x), 63));
}

// Full 64-lane sum via DPP (VALU pipe only); result valid in lane 63 only.
__device__ __forceinline__ int wave_sum64_lane63(int x){
  x += __builtin_amdgcn_update_dpp(0, x, 0x111, 0xF, 0xF, true);
  x += __builtin_amdgcn_update_dpp(0, x, 0x112, 0xF, 0xF, true);
  x += __builtin_amdgcn_update_dpp(0, x, 0x114, 0xF, 0xF, true);
  x += __builtin_amdgcn_update_dpp(0, x, 0x118, 0xF, 0xF, true);
  x += __builtin_amdgcn_update_dpp(0, x, 0x142, 0xF, 0xF, true);
  x += __builtin_amdgcn_update_dpp(0, x, 0x143, 0xF, 0xF, true);
  return x;
}

// ---- 1a: logsumexp stream. grid (B, NLS), 256 threads, 1 prior/thread ----
// Pure memory-bound kernel: 21 loads -> register LSE -> 1 store. Low VGPR +
// 4480 blocks => 8 waves/SIMD, TLP fully hides load latency; runs at HBM floor.
extern "C" __global__ void __launch_bounds__(BTH, 8)
mb_lse(const float* __restrict__ conf_data,
       float* __restrict__ rankneg)
{
  const int b = blockIdx.x;
  const int p = blockIdx.y*BTH + threadIdx.x;
  if (p >= PP) return;
  const float* cb = conf_data + ((long)b*PP + p)*NC;
  const float4* cb4 = reinterpret_cast<const float4*>(cb);  // dwordx4, 4B-aligned ok
  float4 ca0=cb4[0], ca1=cb4[1], ca2=cb4[2], ca3=cb4[3], ca4=cb4[4];
  float c20 = cb[20];
  float vv[NC] = {ca0.x,ca0.y,ca0.z,ca0.w, ca1.x,ca1.y,ca1.z,ca1.w,
                  ca2.x,ca2.y,ca2.z,ca2.w, ca3.x,ca3.y,ca3.z,ca3.w,
                  ca4.x,ca4.y,ca4.z,ca4.w, c20};
  float m = vv[0];
  #pragma unroll
  for (int c=1;c<NC;c++) m = fmaxf(m, vv[c]);
  float s = 0.f;
  #pragma unroll
  for (int c=0;c<NC;c++) s += __expf(vv[c]-m);
  rankneg[(long)b*PP + p] = __logf(s) + m - vv[0];
}

// ---- 1b: match (IoU argmax both directions). grid (B, NCH), 256 threads ----
// Pure VALU kernel: no conf traffic at all. Truths come from UNIFORM (SGPR)
// loads -- zero readlanes, zero in-loop vector-memory. 2 consecutive priors
// per lane (wave = 128 priors) amortizes the per-truth DPP reduce.
// Tie-breaks: lane-local ascending-i strict '>' picks min-p; lane j's priors
// all < lane j+1's, so ballot+ffs+readlane(candp) is global-min-p. OOR priors
// become degenerate far boxes: iou == +0, can only win all-zero ties through
// lanes above every valid lane, which ffs never picks.
extern "C" __global__ void __launch_bounds__(BTH, 8)
mb_match(const float* __restrict__ priors,
         const float* __restrict__ targets,
         unsigned char* __restrict__ meta,
         unsigned long long* __restrict__ keys2)
{
  const int b = blockIdx.x, chunk = blockIdx.y;
  const int tid = threadIdx.x, lane = tid & 63, wid = tid >> 6;
  const int q0w = chunk*CHP + wid*128;           // wave's base prior
  const int p0  = q0w + 2*lane;                  // lane's first prior

  __shared__ unsigned long long s_keys[4][NB];

  const float* tb = targets + (long)b*NB*5;      // uniform -> s_load

  unsigned long long mykey = 0ULL;   // lane n: truth n's winner key for this wave

  if (q0w < PP){
    float bx1[2], by1[2], bx2[2], by2[2], areab[2];
    #pragma unroll
    for (int i=0;i<2;i++){
      int p = p0 + i;
      int pc = (p < PP) ? p : 0;
      float4 pr = reinterpret_cast<const float4*>(priors)[pc];
      float x1 = pr.x - pr.z*0.5f, y1 = pr.y - pr.w*0.5f;
      float x2 = pr.x + pr.z*0.5f, y2 = pr.y + pr.w*0.5f;
      if (p >= PP){ x1=3e9f; y1=3e9f; x2=3e9f; y2=3e9f; }   // iou == +0 exactly
      bx1[i]=x1; by1[i]=y1; bx2[i]=x2; by2[i]=y2;
      areab[i] = (x2-x1)*(y2-y1);
    }

    float bestov[2] = {-1.f,-1.f};
    int   bestn [2] = {0,0};

    #pragma unroll
    for (int n=0;n<NB;n++){
      const float t_x = tb[n*5+0];               // SGPR broadcast (uniform addr)
      const float t_y = tb[n*5+1];
      const float t_z = tb[n*5+2];
      const float t_w = tb[n*5+3];
      const float aa  = (t_z-t_x)*(t_w-t_y);
      float candiou = -1.0f; unsigned candp = 0u;
      #pragma unroll
      for (int i=0;i<2;i++){
        float lx=fmaxf(t_x,bx1[i]), ly=fmaxf(t_y,by1[i]);
        float rx=fminf(t_z,bx2[i]), ry=fminf(t_w,by2[i]);
        float iw=fmaxf(rx-lx,0.f), ih=fmaxf(ry-ly,0.f);
        float inter = iw*ih;
        float iou = inter * __builtin_amdgcn_rcpf(aa + areab[i] - inter);
        if (iou > bestov[i]){ bestov[i]=iou; bestn[i]=n; }         // first-max over n
        if (iou > candiou){ candiou=iou; candp=(unsigned)(p0+i); } // min-p (asc i, strict >)
      }
      // wave argmax for truth n: DPP max + ballot; lowest matching lane = min p.
      // wmax bits == winner's iou bits (fmax over +0/+normals preserves bits).
      float wmax = wave_max64(candiou);
      unsigned long long mk = __ballot(candiou == wmax);   // lane 0 always has candiou>=0
      int wlane = __ffsll((long long)mk) - 1;
      unsigned wp = (unsigned)__builtin_amdgcn_readlane((int)candp, wlane);
      unsigned long long key = ((unsigned long long)__float_as_uint(wmax)<<32)
                             | (unsigned long long)(0xFFFFFFFFu - wp);
      if (lane == n) mykey = key;
    }

    if (p0 < PP){                       // PP even, p0 even => p0+1 < PP too
      unsigned short mb =
          (unsigned short)( ((bestn[0]<<1) | (bestov[0] >= 0.5f ? 1 : 0))
                          | (((bestn[1]<<1) | (bestov[1] >= 0.5f ? 1 : 0)) << 8) );
      *reinterpret_cast<unsigned short*>(meta + (long)b*PP + p0) = mb;  // p0 even => 2B-aligned
    }
  }

  if (lane < NB) s_keys[wid][lane] = mykey;       // out-of-range waves write zeros
  __syncthreads();
  if (tid < NB){
    unsigned long long mx = s_keys[0][tid];
    #pragma unroll
    for (int w=1;w<4;w++) if (s_keys[w][tid] > mx) mx = s_keys[w][tid];
    keys2[((long)b*NCH + chunk)*NB + tid] = mx;
  }
}

// ---- 2: fused scatter + positive losses + top-k + final reduce. grid (B) ----
extern "C" __global__ void __launch_bounds__(BTS)
mb_select(const float* __restrict__ loc_data,
          const float* __restrict__ conf_data,
          const float* __restrict__ priors,
          const float* __restrict__ targets,
          const float* __restrict__ rankneg,
          const unsigned char* __restrict__ meta,
          const unsigned long long* __restrict__ keys2,
          float* __restrict__ rowres, int* __restrict__ ticket,
          float* __restrict__ out, int Bn)
{
  const int b = blockIdx.x, tid = threadIdx.x, lane = tid & 63, wid = tid >> 6;
  __shared__ __align__(16) float s_val[PP];              // 34928
  __shared__ __align__(16) unsigned int s_meta4[PP/4];   // 8732
  __shared__ float4 s_tr4[NB];
  __shared__ float s_lab[NB];
  __shared__ int   s_bp[NB];
  __shared__ int   s_tot[32];                            // per-iteration count slots
  __shared__ float s_fa[NWS], s_fb[NWS], s_fc[NWS];
  __shared__ int   s_ia[NWS];
  __shared__ float s_rowll, s_rowpc;
  __shared__ int   s_npos, s_last;
  unsigned char* s_meta = (unsigned char*)s_meta4;
  float4* sv4 = reinterpret_cast<float4*>(s_val);

  const float4* rr = reinterpret_cast<const float4*>(rankneg + (long)b*PP);
  for (int i=tid;i<PP/4;i+=BTS) sv4[i]=rr[i];
  const unsigned int* mr = reinterpret_cast<const unsigned int*>(meta + (long)b*PP);
  for (int i=tid;i<PP/4;i+=BTS) s_meta4[i]=mr[i];
  if (tid < NB*5){
    int n = tid/5, k2 = tid-n*5;
    float vv = targets[((long)b*NB+n)*5+k2];
    if (k2<4) ((float*)&s_tr4[n])[k2]=vv; else s_lab[n]=vv;
  }
  if (tid < NB){
    unsigned long long mx = 0ULL;
    #pragma unroll
    for (int c=0;c<NCH;c++){
      unsigned long long kk = keys2[((long)b*NCH + c)*NB + tid];
      if (kk > mx) mx = kk;
    }
    s_bp[tid] = (int)(0xFFFFFFFFu - (unsigned)(mx & 0xFFFFFFFFULL));
  }
  if (tid < 32) s_tot[tid] = 0;
  __syncthreads();

  // overrides, ascending n (max n wins on collisions), forced positive
  if (tid==0){
    for (int n=0;n<NB;n++) s_meta[s_bp[n]] = (unsigned char)((n<<1)|1);
  }
  __syncthreads();

  // register-cache rank values; mask positives to 0 (post-override meta)
  float4 rv0 = sv4[tid];
  float4 rv1 = sv4[tid+1024];
  float4 rv2 = (tid < PP/4-2048) ? sv4[tid+2048] : make_float4(0.f,0.f,0.f,0.f);
  unsigned mm0 = s_meta4[tid];
  unsigned mm1 = s_meta4[tid+1024];
  unsigned mm2 = (tid < PP/4-2048) ? s_meta4[tid+2048] : 0u;
  if (mm0 & 0x00000001u) rv0.x = 0.f;
  if (mm0 & 0x00000100u) rv0.y = 0.f;
  if (mm0 & 0x00010000u) rv0.z = 0.f;
  if (mm0 & 0x01000000u) rv0.w = 0.f;
  if (mm1 & 0x00000001u) rv1.x = 0.f;
  if (mm1 & 0x00000100u) rv1.y = 0.f;
  if (mm1 & 0x00010000u) rv1.z = 0.f;
  if (mm1 & 0x01000000u) rv1.w = 0.f;
  if (mm2 & 0x00000001u) rv2.x = 0.f;
  if (mm2 & 0x00000100u) rv2.y = 0.f;
  if (mm2 & 0x00010000u) rv2.z = 0.f;
  if (mm2 & 0x01000000u) rv2.w = 0.f;

  // special case p==0 (clamped.at[0]): tid0-local registers
  int spec = 0; float delta = 0.f, val0 = 0.f;
  if (b==0 && tid==0 && !(mm0 & 1u)){
    float v0 = conf_data[0], v1 = conf_data[1];
    float r0 = rv0.x;                        // lse - v0 = true ce
    float r0p = r0 + v0 - v1;                // lse - v1 = ranking value
    delta = r0 - r0p;
    spec = 1;
    rv0.x = r0p; val0 = r0p;
  }

  // positive pass (identical iteration order; conf refetch is L2-hot)
  float ll=0.f, pc=0.f; int np=0;
  for (int p=tid;p<PP;p+=BTS){
    int mt = s_meta[p];
    if (mt & 1){
      np++;
      int n = mt>>1;
      int ct = (int)s_lab[n] + 1;
      const float* cp = conf_data + ((long)b*PP+p)*NC;
      float v0 = cp[0], vct = cp[ct];
      pc += s_val[p] + v0 - vct;             // lse - v[ct]
      float4 t = s_tr4[n];
      float4 prr = reinterpret_cast<const float4*>(priors)[p];
      float4 ld = reinterpret_cast<const float4*>(loc_data)[(long)b*PP+p];
      float g0 = ((t.x+t.z)*0.5f - prr.x)/(0.1f*prr.z);
      float g1 = ((t.y+t.w)*0.5f - prr.y)/(0.1f*prr.w);
      float g2 = __logf((t.z-t.x)/prr.z)/0.2f;
      float g3 = __logf((t.w-t.y)/prr.w)/0.2f;
      ll += sl1(ld.x-g0)+sl1(ld.y-g1)+sl1(ld.z-g2)+sl1(ld.w-g3);
    }
  }
  #pragma unroll
  for (int o=32;o;o>>=1){
    ll += __shfl_down(ll,o,64);
    pc += __shfl_down(pc,o,64);
    np += __shfl_down(np,o,64);
  }
  if (lane==0){ s_fa[wid]=ll; s_fb[wid]=pc; s_ia[wid]=np; }
  __syncthreads();
  if (tid==0){
    float a=0.f,c2=0.f; int ni=0;
    for (int w=0;w<NWS;w++){ a+=s_fa[w]; c2+=s_fb[w]; ni+=s_ia[w]; }
    s_rowll=a; s_rowpc=c2; s_npos=ni;
  }
  __syncthreads();
  const int num_pos = s_npos;
  int k = num_pos*3; if (k > PP-1) k = PP-1;

  float negsum = 0.f;
  if (k > 0){
    // k-th largest via binary search on float bits; DPP add + one LDS atomic per
    // wave + one broadcast read per iteration.
    unsigned lo=0u, hi=0x7f800000u;
    int it=0;
    while (lo < hi){
      unsigned mid = lo + ((hi - lo + 1u) >> 1);
      int c = (__float_as_uint(rv0.x)>=mid) + (__float_as_uint(rv0.y)>=mid)
            + (__float_as_uint(rv0.z)>=mid) + (__float_as_uint(rv0.w)>=mid)
            + (__float_as_uint(rv1.x)>=mid) + (__float_as_uint(rv1.y)>=mid)
            + (__float_as_uint(rv1.z)>=mid) + (__float_as_uint(rv1.w)>=mid)
            + (__float_as_uint(rv2.x)>=mid) + (__float_as_uint(rv2.y)>=mid)
            + (__float_as_uint(rv2.z)>=mid) + (__float_as_uint(rv2.w)>=mid);
      c = wave_sum64_lane63(c);
      if (lane==63) atomicAdd(&s_tot[it], c);
      __syncthreads();
      int tot = s_tot[it];
      if (tot >= k) lo = mid; else hi = mid - 1u;
      it++;                                   // <=31 iterations, s_tot[32] slots
    }
    const unsigned vstar = lo;

    int cg=0; float sg=0.f;
    #define ACC(x) if (__float_as_uint(x)>vstar){cg++;sg+=(x);}
    ACC(rv0.x) ACC(rv0.y) ACC(rv0.z) ACC(rv0.w)
    ACC(rv1.x) ACC(rv1.y) ACC(rv1.z) ACC(rv1.w)
    ACC(rv2.x) ACC(rv2.y) ACC(rv2.z) ACC(rv2.w)
    #undef ACC
    #pragma unroll
    for (int o=32;o;o>>=1){ cg += __shfl_down(cg,o,64); sg += __shfl_down(sg,o,64); }
    __syncthreads();
    if (lane==0){ s_ia[wid]=cg; s_fa[wid]=sg; }
    __syncthreads();
    if (tid==0){
      int cG=0; float sumG=0.f;
      for (int w=0;w<NWS;w++){ cG+=s_ia[w]; sumG+=s_fa[w]; }
      int tie = k - cG;                      // >=1; stable ties take lowest indices
      negsum = sumG + (float)tie * __uint_as_float(vstar);
      if (b==0 && spec && __float_as_uint(val0) >= vstar) negsum += delta;
    }
  }

  if (tid==0){
    rowres[b*4+0] = s_rowll;
    rowres[b*4+1] = s_rowpc + negsum;
    rowres[b*4+2] = (float)num_pos;
    __threadfence();
    int t = atomicAdd(ticket, 1);
    s_last = (t == Bn - 1) ? 1 : 0;
  }
  __syncthreads();

  if (s_last){
    __threadfence();
    float a0=0.f, a1=0.f, a2=0.f;
    for (int i=tid;i<Bn;i+=BTS){
      a0 += rowres[i*4+0]; a1 += rowres[i*4+1]; a2 += rowres[i*4+2];
    }
    #pragma unroll
    for (int o=32;o;o>>=1){
      a0 += __shfl_down(a0,o,64);
      a1 += __shfl_down(a1,o,64);
      a2 += __shfl_down(a2,o,64);
    }
    if (lane==0){ s_fa[wid]=a0; s_fb[wid]=a1; s_fc[wid]=a2; }
    __syncthreads();
    if (tid==0){
      float A0=0.f,A1=0.f,A2=0.f;
      for (int w=0;w<NWS;w++){ A0+=s_fa[w]; A1+=s_fb[w]; A2+=s_fc[w]; }
      out[0] = A0/A2;
      out[1] = A1/A2;
    }
  }
}

extern "C" void kernel_launch(void* const* d_in, const int* in_sizes, int n_in,
                              void* d_out, int out_size, void* d_ws, size_t ws_size,
                              hipStream_t stream) {
  const float* loc     = (const float*)d_in[0];
  const float* conf    = (const float*)d_in[1];
  const float* priors  = (const float*)d_in[2];
  const float* targets = (const float*)d_in[3];
  float* out = (float*)d_out;
  int B = in_sizes[0] / (PP*4);

  char* ws = (char*)d_ws;
  int*   ticket = (int*)ws;
  float* rowres = (float*)(ws + 64);
  unsigned long long* keys2 = (unsigned long long*)(ws + 4096);
  size_t off_rank = (4096 + (size_t)B*NCH*NB*8 + 255) & ~(size_t)255;
  float* rankneg = (float*)(ws + off_rank);
  unsigned char* metaa = (unsigned char*)(ws + off_rank + (size_t)B*PP*4);

  hipMemsetAsync(d_ws, 0, 64, stream);
  hipLaunchKernelGGL(mb_lse,    dim3(B, NLS), dim3(BTH), 0, stream,
                     conf, rankneg);
  hipLaunchKernelGGL(mb_match,  dim3(B, NCH), dim3(BTH), 0, stream,
                     priors, targets, metaa, keys2);
  hipLaunchKernelGGL(mb_select, dim3(B), dim3(BTS), 0, stream,
                     loc, conf, priors, targets, rankneg, metaa, keys2,
                     rowres, ticket, out, B);
}

// Round 7
// 199.234 us; speedup vs baseline: 1.0903x; 1.0903x over previous
//
#include <hip/hip_runtime.h>

#define PP 8732
#define NB 20
#define NC 21
#define BTH 256
#define CHP 512         // match: priors per block (2 per lane, 128 per wave)
#define NCH 18          // ceil(PP/CHP)
#define NLS 9           // lse: ceil(PP/1024), 4 priors/thread
#define BTS 1024
#define NWS (BTS/64)

__device__ __forceinline__ float sl1(float d){
  float a = fabsf(d);
  return a < 1.0f ? 0.5f*a*a : a - 0.5f;
}

// Full 64-lane max via DPP (VALU pipe only); result valid in lane 63, broadcast
// to all lanes through readlane. bound_ctrl=1 injects 0.0 at row edges -- harmless
// here since every participating value is >= 0 (candiou is an IoU >= 0).
__device__ __forceinline__ float wave_max64(float x){
  int t;
  t = __builtin_amdgcn_update_dpp(0, __float_as_int(x), 0x111, 0xF, 0xF, true); x = fmaxf(x, __int_as_float(t));
  t = __builtin_amdgcn_update_dpp(0, __float_as_int(x), 0x112, 0xF, 0xF, true); x = fmaxf(x, __int_as_float(t));
  t = __builtin_amdgcn_update_dpp(0, __float_as_int(x), 0x114, 0xF, 0xF, true); x = fmaxf(x, __int_as_float(t));
  t = __builtin_amdgcn_update_dpp(0, __float_as_int(x), 0x118, 0xF, 0xF, true); x = fmaxf(x, __int_as_float(t));
  t = __builtin_amdgcn_update_dpp(0, __float_as_int(x), 0x142, 0xF, 0xF, true); x = fmaxf(x, __int_as_float(t));
  t = __builtin_amdgcn_update_dpp(0, __float_as_int(x), 0x143, 0xF, 0xF, true); x = fmaxf(x, __int_as_float(t));
  return __int_as_float(__builtin_amdgcn_readlane(__float_as_int(x), 63));
}

// Full 64-lane sum via DPP (VALU pipe only); result valid in lane 63 only.
__device__ __forceinline__ int wave_sum64_lane63(int x){
  x += __builtin_amdgcn_update_dpp(0, x, 0x111, 0xF, 0xF, true);
  x += __builtin_amdgcn_update_dpp(0, x, 0x112, 0xF, 0xF, true);
  x += __builtin_amdgcn_update_dpp(0, x, 0x114, 0xF, 0xF, true);
  x += __builtin_amdgcn_update_dpp(0, x, 0x118, 0xF, 0xF, true);
  x += __builtin_amdgcn_update_dpp(0, x, 0x142, 0xF, 0xF, true);
  x += __builtin_amdgcn_update_dpp(0, x, 0x143, 0xF, 0xF, true);
  return x;
}

// ---- 1: block-specialized match + LSE in ONE launch. grid (B, NCH+NLS) ----
// Blocks y<NCH: pure-VALU match (SGPR-uniform truths, zero conf traffic).
// Blocks y>=NCH: pure-stream LSE (21 loads -> register LSE -> 1 store,
// 4 priors/thread). Block-uniform branch, both paths <=64 VGPR (8 waves/SIMD).
// Memory-heavy and VALU-heavy blocks co-schedule across CUs: the decoupling
// R6 proved, without R6's extra launch boundary.
extern "C" __global__ void __launch_bounds__(BTH, 8)
mb_main(const float* __restrict__ conf_data,
        const float* __restrict__ priors,
        const float* __restrict__ targets,
        float* __restrict__ rankneg,
        unsigned char* __restrict__ meta,
        unsigned long long* __restrict__ keys2)
{
  const int b = blockIdx.x, y = blockIdx.y;

  if (y >= NCH){
    // -------- LSE path --------
    const int base = (y - NCH)*1024;
    #pragma unroll
    for (int k=0;k<4;k++){
      const int p = base + k*BTH + threadIdx.x;
      if (p < PP){
        const float* cb = conf_data + ((long)b*PP + p)*NC;
        const float4* cb4 = reinterpret_cast<const float4*>(cb);  // dwordx4, 4B-aligned ok
        float4 ca0=cb4[0], ca1=cb4[1], ca2=cb4[2], ca3=cb4[3], ca4=cb4[4];
        float c20 = cb[20];
        float vv[NC] = {ca0.x,ca0.y,ca0.z,ca0.w, ca1.x,ca1.y,ca1.z,ca1.w,
                        ca2.x,ca2.y,ca2.z,ca2.w, ca3.x,ca3.y,ca3.z,ca3.w,
                        ca4.x,ca4.y,ca4.z,ca4.w, c20};
        float m = vv[0];
        #pragma unroll
        for (int c=1;c<NC;c++) m = fmaxf(m, vv[c]);
        float s = 0.f;
        #pragma unroll
        for (int c=0;c<NC;c++) s += __expf(vv[c]-m);
        rankneg[(long)b*PP + p] = __logf(s) + m - vv[0];
      }
    }
    return;
  }

  // -------- match path --------
  const int chunk = y;
  const int tid = threadIdx.x, lane = tid & 63, wid = tid >> 6;
  const int q0w = chunk*CHP + wid*128;           // wave's base prior
  const int p0  = q0w + 2*lane;                  // lane's first prior

  __shared__ unsigned long long s_keys[4][NB];

  const float* tb = targets + (long)b*NB*5;      // uniform -> s_load

  unsigned long long mykey = 0ULL;   // lane n: truth n's winner key for this wave

  if (q0w < PP){
    float bx1[2], by1[2], bx2[2], by2[2], areab[2];
    #pragma unroll
    for (int i=0;i<2;i++){
      int p = p0 + i;
      int pc = (p < PP) ? p : 0;
      float4 pr = reinterpret_cast<const float4*>(priors)[pc];
      float x1 = pr.x - pr.z*0.5f, y1 = pr.y - pr.w*0.5f;
      float x2 = pr.x + pr.z*0.5f, y2 = pr.y + pr.w*0.5f;
      if (p >= PP){ x1=3e9f; y1=3e9f; x2=3e9f; y2=3e9f; }   // iou == +0 exactly
      bx1[i]=x1; by1[i]=y1; bx2[i]=x2; by2[i]=y2;
      areab[i] = (x2-x1)*(y2-y1);
    }

    float bestov[2] = {-1.f,-1.f};
    int   bestn [2] = {0,0};

    #pragma unroll
    for (int n=0;n<NB;n++){
      const float t_x = tb[n*5+0];               // SGPR broadcast (uniform addr)
      const float t_y = tb[n*5+1];
      const float t_z = tb[n*5+2];
      const float t_w = tb[n*5+3];
      const float aa  = (t_z-t_x)*(t_w-t_y);
      float candiou = -1.0f; unsigned candp = 0u;
      #pragma unroll
      for (int i=0;i<2;i++){
        float lx=fmaxf(t_x,bx1[i]), ly=fmaxf(t_y,by1[i]);
        float rx=fminf(t_z,bx2[i]), ry=fminf(t_w,by2[i]);
        float iw=fmaxf(rx-lx,0.f), ih=fmaxf(ry-ly,0.f);
        float inter = iw*ih;
        float iou = inter * __builtin_amdgcn_rcpf(aa + areab[i] - inter);
        if (iou > bestov[i]){ bestov[i]=iou; bestn[i]=n; }         // first-max over n
        if (iou > candiou){ candiou=iou; candp=(unsigned)(p0+i); } // min-p (asc i, strict >)
      }
      // wave argmax for truth n: DPP max + ballot; lowest matching lane = min p.
      // wmax bits == winner's iou bits (fmax over +0/+normals preserves bits).
      float wmax = wave_max64(candiou);
      unsigned long long mk = __ballot(candiou == wmax);   // lane 0 always has candiou>=0
      int wlane = __ffsll((long long)mk) - 1;
      unsigned wp = (unsigned)__builtin_amdgcn_readlane((int)candp, wlane);
      unsigned long long key = ((unsigned long long)__float_as_uint(wmax)<<32)
                             | (unsigned long long)(0xFFFFFFFFu - wp);
      if (lane == n) mykey = key;
    }

    if (p0 < PP){                       // PP even, p0 even => p0+1 < PP too
      unsigned short mb =
          (unsigned short)( ((bestn[0]<<1) | (bestov[0] >= 0.5f ? 1 : 0))
                          | (((bestn[1]<<1) | (bestov[1] >= 0.5f ? 1 : 0)) << 8) );
      *reinterpret_cast<unsigned short*>(meta + (long)b*PP + p0) = mb;  // p0 even => 2B-aligned
    }
  }

  if (lane < NB) s_keys[wid][lane] = mykey;       // out-of-range waves write zeros
  __syncthreads();
  if (tid < NB){
    unsigned long long mx = s_keys[0][tid];
    #pragma unroll
    for (int w=1;w<4;w++) if (s_keys[w][tid] > mx) mx = s_keys[w][tid];
    keys2[((long)b*NCH + chunk)*NB + tid] = mx;
  }
}

// ---- 2: fused scatter + positive losses + top-k + final reduce. grid (B) ----
extern "C" __global__ void __launch_bounds__(BTS)
mb_select(const float* __restrict__ loc_data,
          const float* __restrict__ conf_data,
          const float* __restrict__ priors,
          const float* __restrict__ targets,
          const float* __restrict__ rankneg,
          const unsigned char* __restrict__ meta,
          const unsigned long long* __restrict__ keys2,
          float* __restrict__ rowres, int* __restrict__ ticket,
          float* __restrict__ out, int Bn)
{
  const int b = blockIdx.x, tid = threadIdx.x, lane = tid & 63, wid = tid >> 6;
  __shared__ __align__(16) float s_val[PP];              // 34928
  __shared__ __align__(16) unsigned int s_meta4[PP/4];   // 8732
  __shared__ float4 s_tr4[NB];
  __shared__ float s_lab[NB];
  __shared__ int   s_bp[NB];
  __shared__ int   s_tot[32];                            // per-iteration count slots
  __shared__ float s_fa[NWS], s_fb[NWS], s_fc[NWS];
  __shared__ int   s_ia[NWS];
  __shared__ float s_rowll, s_rowpc;
  __shared__ int   s_npos, s_last;
  unsigned char* s_meta = (unsigned char*)s_meta4;
  float4* sv4 = reinterpret_cast<float4*>(s_val);

  const float4* rr = reinterpret_cast<const float4*>(rankneg + (long)b*PP);
  for (int i=tid;i<PP/4;i+=BTS) sv4[i]=rr[i];
  const unsigned int* mr = reinterpret_cast<const unsigned int*>(meta + (long)b*PP);
  for (int i=tid;i<PP/4;i+=BTS) s_meta4[i]=mr[i];
  if (tid < NB*5){
    int n = tid/5, k2 = tid-n*5;
    float vv = targets[((long)b*NB+n)*5+k2];
    if (k2<4) ((float*)&s_tr4[n])[k2]=vv; else s_lab[n]=vv;
  }
  if (tid < NB){
    unsigned long long mx = 0ULL;
    #pragma unroll
    for (int c=0;c<NCH;c++){
      unsigned long long kk = keys2[((long)b*NCH + c)*NB + tid];
      if (kk > mx) mx = kk;
    }
    s_bp[tid] = (int)(0xFFFFFFFFu - (unsigned)(mx & 0xFFFFFFFFULL));
  }
  if (tid < 32) s_tot[tid] = 0;
  __syncthreads();

  // overrides, ascending n (max n wins on collisions), forced positive
  if (tid==0){
    for (int n=0;n<NB;n++) s_meta[s_bp[n]] = (unsigned char)((n<<1)|1);
  }
  __syncthreads();

  // register-cache rank values; mask positives to 0 (post-override meta)
  float4 rv0 = sv4[tid];
  float4 rv1 = sv4[tid+1024];
  float4 rv2 = (tid < PP/4-2048) ? sv4[tid+2048] : make_float4(0.f,0.f,0.f,0.f);
  unsigned mm0 = s_meta4[tid];
  unsigned mm1 = s_meta4[tid+1024];
  unsigned mm2 = (tid < PP/4-2048) ? s_meta4[tid+2048] : 0u;
  if (mm0 & 0x00000001u) rv0.x = 0.f;
  if (mm0 & 0x00000100u) rv0.y = 0.f;
  if (mm0 & 0x00010000u) rv0.z = 0.f;
  if (mm0 & 0x01000000u) rv0.w = 0.f;
  if (mm1 & 0x00000001u) rv1.x = 0.f;
  if (mm1 & 0x00000100u) rv1.y = 0.f;
  if (mm1 & 0x00010000u) rv1.z = 0.f;
  if (mm1 & 0x01000000u) rv1.w = 0.f;
  if (mm2 & 0x00000001u) rv2.x = 0.f;
  if (mm2 & 0x00000100u) rv2.y = 0.f;
  if (mm2 & 0x00010000u) rv2.z = 0.f;
  if (mm2 & 0x01000000u) rv2.w = 0.f;

  // special case p==0 (clamped.at[0]): tid0-local registers
  int spec = 0; float delta = 0.f, val0 = 0.f;
  if (b==0 && tid==0 && !(mm0 & 1u)){
    float v0 = conf_data[0], v1 = conf_data[1];
    float r0 = rv0.x;                        // lse - v0 = true ce
    float r0p = r0 + v0 - v1;                // lse - v1 = ranking value
    delta = r0 - r0p;
    spec = 1;
    rv0.x = r0p; val0 = r0p;
  }

  // positive pass (identical iteration order; conf refetch is L2-hot)
  float ll=0.f, pc=0.f; int np=0;
  for (int p=tid;p<PP;p+=BTS){
    int mt = s_meta[p];
    if (mt & 1){
      np++;
      int n = mt>>1;
      int ct = (int)s_lab[n] + 1;
      const float* cp = conf_data + ((long)b*PP+p)*NC;
      float v0 = cp[0], vct = cp[ct];
      pc += s_val[p] + v0 - vct;             // lse - v[ct]
      float4 t = s_tr4[n];
      float4 prr = reinterpret_cast<const float4*>(priors)[p];
      float4 ld = reinterpret_cast<const float4*>(loc_data)[(long)b*PP+p];
      float g0 = ((t.x+t.z)*0.5f - prr.x)/(0.1f*prr.z);
      float g1 = ((t.y+t.w)*0.5f - prr.y)/(0.1f*prr.w);
      float g2 = __logf((t.z-t.x)/prr.z)/0.2f;
      float g3 = __logf((t.w-t.y)/prr.w)/0.2f;
      ll += sl1(ld.x-g0)+sl1(ld.y-g1)+sl1(ld.z-g2)+sl1(ld.w-g3);
    }
  }
  #pragma unroll
  for (int o=32;o;o>>=1){
    ll += __shfl_down(ll,o,64);
    pc += __shfl_down(pc,o,64);
    np += __shfl_down(np,o,64);
  }
  if (lane==0){ s_fa[wid]=ll; s_fb[wid]=pc; s_ia[wid]=np; }
  __syncthreads();
  if (tid==0){
    float a=0.f,c2=0.f; int ni=0;
    for (int w=0;w<NWS;w++){ a+=s_fa[w]; c2+=s_fb[w]; ni+=s_ia[w]; }
    s_rowll=a; s_rowpc=c2; s_npos=ni;
  }
  __syncthreads();
  const int num_pos = s_npos;
  int k = num_pos*3; if (k > PP-1) k = PP-1;

  float negsum = 0.f;
  if (k > 0){
    // k-th largest via binary search on float bits; DPP add + one LDS atomic per
    // wave + one broadcast read per iteration.
    unsigned lo=0u, hi=0x7f800000u;
    int it=0;
    while (lo < hi){
      unsigned mid = lo + ((hi - lo + 1u) >> 1);
      int c = (__float_as_uint(rv0.x)>=mid) + (__float_as_uint(rv0.y)>=mid)
            + (__float_as_uint(rv0.z)>=mid) + (__float_as_uint(rv0.w)>=mid)
            + (__float_as_uint(rv1.x)>=mid) + (__float_as_uint(rv1.y)>=mid)
            + (__float_as_uint(rv1.z)>=mid) + (__float_as_uint(rv1.w)>=mid)
            + (__float_as_uint(rv2.x)>=mid) + (__float_as_uint(rv2.y)>=mid)
            + (__float_as_uint(rv2.z)>=mid) + (__float_as_uint(rv2.w)>=mid);
      c = wave_sum64_lane63(c);
      if (lane==63) atomicAdd(&s_tot[it], c);
      __syncthreads();
      int tot = s_tot[it];
      if (tot >= k) lo = mid; else hi = mid - 1u;
      it++;                                   // <=31 iterations, s_tot[32] slots
    }
    const unsigned vstar = lo;

    int cg=0; float sg=0.f;
    #define ACC(x) if (__float_as_uint(x)>vstar){cg++;sg+=(x);}
    ACC(rv0.x) ACC(rv0.y) ACC(rv0.z) ACC(rv0.w)
    ACC(rv1.x) ACC(rv1.y) ACC(rv1.z) ACC(rv1.w)
    ACC(rv2.x) ACC(rv2.y) ACC(rv2.z) ACC(rv2.w)
    #undef ACC
    #pragma unroll
    for (int o=32;o;o>>=1){ cg += __shfl_down(cg,o,64); sg += __shfl_down(sg,o,64); }
    __syncthreads();
    if (lane==0){ s_ia[wid]=cg; s_fa[wid]=sg; }
    __syncthreads();
    if (tid==0){
      int cG=0; float sumG=0.f;
      for (int w=0;w<NWS;w++){ cG+=s_ia[w]; sumG+=s_fa[w]; }
      int tie = k - cG;                      // >=1; stable ties take lowest indices
      negsum = sumG + (float)tie * __uint_as_float(vstar);
      if (b==0 && spec && __float_as_uint(val0) >= vstar) negsum += delta;
    }
  }

  if (tid==0){
    rowres[b*4+0] = s_rowll;
    rowres[b*4+1] = s_rowpc + negsum;
    rowres[b*4+2] = (float)num_pos;
    __threadfence();
    int t = atomicAdd(ticket, 1);
    s_last = (t == Bn - 1) ? 1 : 0;
  }
  __syncthreads();

  if (s_last){
    __threadfence();
    float a0=0.f, a1=0.f, a2=0.f;
    for (int i=tid;i<Bn;i+=BTS){
      a0 += rowres[i*4+0]; a1 += rowres[i*4+1]; a2 += rowres[i*4+2];
    }
    #pragma unroll
    for (int o=32;o;o>>=1){
      a0 += __shfl_down(a0,o,64);
      a1 += __shfl_down(a1,o,64);
      a2 += __shfl_down(a2,o,64);
    }
    if (lane==0){ s_fa[wid]=a0; s_fb[wid]=a1; s_fc[wid]=a2; }
    __syncthreads();
    if (tid==0){
      float A0=0.f,A1=0.f,A2=0.f;
      for (int w=0;w<NWS;w++){ A0+=s_fa[w]; A1+=s_fb[w]; A2+=s_fc[w]; }
      out[0] = A0/A2;
      out[1] = A1/A2;
    }
  }
}

extern "C" void kernel_launch(void* const* d_in, const int* in_sizes, int n_in,
                              void* d_out, int out_size, void* d_ws, size_t ws_size,
                              hipStream_t stream) {
  const float* loc     = (const float*)d_in[0];
  const float* conf    = (const float*)d_in[1];
  const float* priors  = (const float*)d_in[2];
  const float* targets = (const float*)d_in[3];
  float* out = (float*)d_out;
  int B = in_sizes[0] / (PP*4);

  char* ws = (char*)d_ws;
  int*   ticket = (int*)ws;
  float* rowres = (float*)(ws + 64);
  unsigned long long* keys2 = (unsigned long long*)(ws + 4096);
  size_t off_rank = (4096 + (size_t)B*NCH*NB*8 + 255) & ~(size_t)255;
  float* rankneg = (float*)(ws + off_rank);
  unsigned char* metaa = (unsigned char*)(ws + off_rank + (size_t)B*PP*4);

  hipMemsetAsync(d_ws, 0, 64, stream);
  hipLaunchKernelGGL(mb_main,   dim3(B, NCH+NLS), dim3(BTH), 0, stream,
                     conf, priors, targets, rankneg, metaa, keys2);
  hipLaunchKernelGGL(mb_select, dim3(B), dim3(BTS), 0, stream,
                     loc, conf, priors, targets, rankneg, metaa, keys2,
                     rowres, ticket, out, B);
}